// Round 7
// baseline (509.312 us; speedup 1.0000x reference)
//
#include <hip/hip_runtime.h>
#include <math.h>

#define N_NODES 100000
#define N_EDGES 1600000
#define F_INF   128
#define HIDF    128

#define MLP_BLOCKS  2048
#define CAST_BLOCKS 12500                     // N*128/4/256
#define WP_BASE     (CAST_BLOCKS + MLP_BLOCKS) // 14548
#define FRONT_GRID  (WP_BASE + 256)            // + 2x128 wpack blocks

typedef __attribute__((ext_vector_type(8)))  short short8;
typedef __attribute__((ext_vector_type(16))) float floatx16;

__device__ __forceinline__ unsigned short f2bf(float f) {
    unsigned u = __float_as_uint(f);
    return (unsigned short)((u + 0x7FFFu + ((u >> 16) & 1u)) >> 16);
}
__device__ __forceinline__ float bf2f(unsigned short h) {
    return __uint_as_float((unsigned)h << 16);
}

// ---------------------------------------------------------------- FRONT (merged)
// Verified round-4/6 version (~101 us): cast+degree-atomic / edge-MLP / wpack.
__global__ __launch_bounds__(256) void k_front(
        const float* __restrict__ x,
        unsigned short* __restrict__ xbHi, unsigned short* __restrict__ xbLo,
        const int* __restrict__ dst, int* __restrict__ deg,
        unsigned char* __restrict__ rank,
        const float* __restrict__ ea,
        const float* __restrict__ mw1, const float* __restrict__ mb1,
        const float* __restrict__ mw2, const float* __restrict__ mb2,
        float* __restrict__ ew,
        const float* __restrict__ w1l, const float* __restrict__ w1r,
        short* __restrict__ W1hi, short* __restrict__ W1lo,
        const float* __restrict__ w2l, const float* __restrict__ w2r,
        short* __restrict__ W2hi, short* __restrict__ W2lo) {
    const int bid = blockIdx.x;

    if (bid >= WP_BASE) {
        const int wb  = bid - WP_BASE;                   // 0..255
        const int idx = (wb & 127) * 256 + threadIdx.x;  // 0..32767
        const float* Wl = (wb < 128) ? w1l : w2l;
        const float* Wr = (wb < 128) ? w1r : w2r;
        short* Whi = (wb < 128) ? W1hi : W2hi;
        short* Wlo = (wb < 128) ? W1lo : W2lo;
        const int j  = idx & 7;
        const int L  = (idx >> 3) & 63;
        const int cb = (idx >> 9) & 3;
        const int kb = (idx >> 11);
        const int k  = kb * 16 + (L >> 5) * 8 + j;
        const int n  = cb * 32 + (L & 31);
        const float a = (k < 128) ? Wl[k * 128 + n] : Wr[(k - 128) * 128 + n];
        const unsigned short hb = f2bf(a);
        Whi[idx] = (short)hb;
        Wlo[idx] = (short)f2bf(a - bf2f(hb));
        return;
    }

    const bool is_mlp = ((bid % 7) == 3) && (bid < 7 * MLP_BLOCKS);
    if (!is_mlp) {
        const int c   = (bid < 4) ? 0 : min(MLP_BLOCKS, (bid - 4) / 7 + 1);
        const int gid = (bid - c) * 256 + (int)threadIdx.x;   // 0 .. 3.2M-1
        const int i   = gid * 4;                              // N*128 exactly
        const float4 v = *(const float4*)(x + i);
        ushort4 h, l;
        h.x = f2bf(v.x); l.x = f2bf(v.x - bf2f(h.x));
        h.y = f2bf(v.y); l.y = f2bf(v.y - bf2f(h.y));
        h.z = f2bf(v.z); l.z = f2bf(v.z - bf2f(h.z));
        h.w = f2bf(v.w); l.w = f2bf(v.w - bf2f(h.w));
        *(ushort4*)(xbHi + i) = h;
        *(ushort4*)(xbLo + i) = l;
        if ((gid & 1) == 0) {
            const int e = gid >> 1;                           // covers all 1.6M edges
            rank[e] = (unsigned char)atomicAdd(&deg[dst[e]], 1);
        }
        return;
    }

    // ---- edge MLP (wave = 32 edges; grid-stride over 8192 waves) ----
    const int lane = threadIdx.x & 63;
    const int cl   = lane & 31;
    const int half = lane >> 5;
    const int wid  = (bid / 7) * 4 + ((int)threadIdx.x >> 6);
    const int nw   = MLP_BLOCKS * 4;

    short8 bw[4];
    float  w2c[4];
#pragma unroll
    for (int cb = 0; cb < 4; ++cb) {
        const int n = cb * 32 + cl;
        short8 b;
        if (half == 0) {
#pragma unroll
            for (int j = 0; j < 8; ++j) b[j] = (short)f2bf(mw1[j * 128 + n]);
        } else {
            b[0] = (short)f2bf(mb1[n]);
#pragma unroll
            for (int j = 1; j < 8; ++j) b[j] = 0;
        }
        bw[cb] = b;
        w2c[cb] = mw2[n];
    }
    short8 Abias;
    Abias[0] = (short)0x3F80;
#pragma unroll
    for (int j = 1; j < 8; ++j) Abias[j] = 0;

    floatx16 czero;
#pragma unroll
    for (int r = 0; r < 16; ++r) czero[r] = 0.f;

    const float bias2 = mb2[0];

    for (int e0 = wid * 32; e0 < N_EDGES; e0 += nw * 32) {
        short8 Ah;
        if (half == 0) {
            const float4 a0 = *(const float4*)(ea + (size_t)(e0 + cl) * 8);
            const float4 a1 = *(const float4*)(ea + (size_t)(e0 + cl) * 8 + 4);
            Ah[0] = (short)f2bf(a0.x); Ah[1] = (short)f2bf(a0.y);
            Ah[2] = (short)f2bf(a0.z); Ah[3] = (short)f2bf(a0.w);
            Ah[4] = (short)f2bf(a1.x); Ah[5] = (short)f2bf(a1.y);
            Ah[6] = (short)f2bf(a1.z); Ah[7] = (short)f2bf(a1.w);
        } else {
            Ah = Abias;
        }

        float z[16];
#pragma unroll
        for (int r = 0; r < 16; ++r) z[r] = 0.f;

#pragma unroll
        for (int cb = 0; cb < 4; ++cb) {
            floatx16 acc = __builtin_amdgcn_mfma_f32_32x32x16_bf16(Ah, bw[cb], czero, 0, 0, 0);
#pragma unroll
            for (int r = 0; r < 16; ++r)
                z[r] = fmaf(fmaxf(acc[r], 0.f), w2c[cb], z[r]);
        }

#pragma unroll
        for (int m = 1; m <= 16; m <<= 1) {
#pragma unroll
            for (int r = 0; r < 16; ++r) z[r] += __shfl_xor(z[r], m, 64);
        }

        float zz = z[0];
#pragma unroll
        for (int r = 1; r < 16; ++r) zz = (cl == r) ? z[r] : zz;
        if (cl < 16) {
            const int row = (cl & 3) + 8 * (cl >> 2) + 4 * half;
            ew[e0 + row] = 1.f / (1.f + __expf(-(zz + bias2)));
        }
    }
}

// ---------------------------------------------------------------- CSR build
__global__ void k_scan1(const int* __restrict__ deg, int* __restrict__ incl,
                        int* __restrict__ bsum) {
    __shared__ int sm[1024];
    const int tid = threadIdx.x;
    const int gi  = blockIdx.x * 1024 + tid;
    int v = (gi < N_NODES) ? deg[gi] : 0;
    sm[tid] = v;
    __syncthreads();
    for (int off = 1; off < 1024; off <<= 1) {
        int t = (tid >= off) ? sm[tid - off] : 0;
        __syncthreads();
        sm[tid] += t;
        __syncthreads();
    }
    if (gi < N_NODES) incl[gi] = sm[tid];
    if (tid == 1023) bsum[blockIdx.x] = sm[1023];
}

__global__ void k_scan23(const int* __restrict__ incl, const int* __restrict__ bsum,
                         int* __restrict__ rowptr, int nb) {
    __shared__ int sm[128];
    const int tid = threadIdx.x;   // 256
    int v = 0;
    if (tid < 128) {
        v = (tid < nb) ? bsum[tid] : 0;
        sm[tid] = v;
    }
    __syncthreads();
    for (int off = 1; off < 128; off <<= 1) {
        int t = 0;
        if (tid < 128 && tid >= off) t = sm[tid - off];
        __syncthreads();
        if (tid < 128) sm[tid] += t;
        __syncthreads();
    }
    if (tid < 128) sm[tid] -= v;   // exclusive block offset
    __syncthreads();
    const int i = blockIdx.x * 256 + tid;
    if (i < N_NODES) rowptr[i + 1] = sm[i >> 10] + incl[i];
    if (i == 0) rowptr[0] = 0;
}

__global__ void k_fill(const int* __restrict__ src, const int* __restrict__ dst,
                       const float* __restrict__ ew, const int* __restrict__ rowptr,
                       const unsigned char* __restrict__ rank,
                       unsigned* __restrict__ cw) {
    int e = blockIdx.x * 256 + threadIdx.x;
    if (e < N_EDGES) {
        int d   = dst[e];
        int pos = rowptr[d] + (int)rank[e];
        unsigned wb = (unsigned)f2bf(ew[e]) & 0x7FFFu;
        cw[pos] = ((unsigned)src[e] << 15) | wb;
    }
}

// ---------------------------------------------------------------- FUSED gather + GEMM
// Round-1's fusion failed at 64-thr blocks / 1 wave gathering 32 nodes (16%
// occupancy). This version: 256-thr blocks, 4 waves x 8 nodes each, gather
// written straight into the swizzled SH/SL tile the gemm already stages
// through (round-1-verified write pattern; round-4-verified read pattern) ->
// deletes aggHi/aggLo (102 MB traffic) + 2 dispatches, and gather (L3 stream)
// overlaps gemm (L2 W-stream + MFMA) across resident blocks.
// GEMM_BODY: gather phase + root staging + agg/root MFMA phases, leaves acc.
#define GEMM_BODY(tabHi, tabLo)                                                  \
    const int tid  = threadIdx.x;                                                \
    const int lane = tid & 63;                                                   \
    const int cb   = tid >> 6;                                                   \
    const int half = lane >> 5;                                                  \
    const int cl   = lane & 31;                                                  \
    const int rrow = cl;                                                         \
    const int kq   = half;                                                       \
    const int row0 = blockIdx.x * 32;                                            \
    for (int i = 0; i < 8; ++i) {                                                \
        const int nl = cb * 8 + i;                                               \
        const int node = row0 + nl;                                              \
        const int s = rowptr[node], e = rowptr[node + 1];                        \
        float a0 = 0.f, a1 = 0.f, a2 = 0.f, a3 = 0.f;                            \
        for (int j0 = s; j0 < e; j0 += 8) {                                      \
            int ss[4]; float ww[4];                                              \
            _Pragma("unroll")                                                    \
            for (int u = 0; u < 4; ++u) {                                        \
                const int j  = j0 + 2 * u + half;                                \
                const int jc = min(j, e - 1);                                    \
                const unsigned p = cw[jc];                                       \
                ss[u] = (int)(p >> 15);                                          \
                ww[u] = (j < e) ? __uint_as_float((p & 0x7FFFu) << 16) : 0.f;    \
            }                                                                    \
            uint2 g[4];                                                          \
            _Pragma("unroll")                                                    \
            for (int u = 0; u < 4; ++u)                                          \
                g[u] = *(const uint2*)(tabHi + (size_t)ss[u] * 128 + cl * 4);    \
            _Pragma("unroll")                                                    \
            for (int u = 0; u < 4; ++u) {                                        \
                const float f0 = __uint_as_float(g[u].x << 16);                  \
                const float f1 = __uint_as_float(g[u].x & 0xFFFF0000u);          \
                const float f2 = __uint_as_float(g[u].y << 16);                  \
                const float f3 = __uint_as_float(g[u].y & 0xFFFF0000u);          \
                a0 = fmaf(ww[u], f0, a0);                                        \
                a1 = fmaf(ww[u], f1, a1);                                        \
                a2 = fmaf(ww[u], f2, a2);                                        \
                a3 = fmaf(ww[u], f3, a3);                                        \
            }                                                                    \
        }                                                                        \
        a0 += __shfl_xor(a0, 32, 64);                                            \
        a1 += __shfl_xor(a1, 32, 64);                                            \
        a2 += __shfl_xor(a2, 32, 64);                                            \
        a3 += __shfl_xor(a3, 32, 64);                                            \
        const float inv = 1.f / fmaxf((float)(e - s), 1.f);                      \
        a0 *= inv; a1 *= inv; a2 *= inv; a3 *= inv;                              \
        unsigned short v0, v1, v2, v3;                                           \
        if (half == 0) {                                                         \
            v0 = f2bf(a0); v1 = f2bf(a1); v2 = f2bf(a2); v3 = f2bf(a3);          \
        } else {                                                                 \
            const unsigned short h0 = f2bf(a0), h1 = f2bf(a1),                   \
                                 h2 = f2bf(a2), h3 = f2bf(a3);                   \
            v0 = f2bf(a0 - bf2f(h0)); v1 = f2bf(a1 - bf2f(h1));                  \
            v2 = f2bf(a2 - bf2f(h2)); v3 = f2bf(a3 - bf2f(h3));                  \
        }                                                                        \
        uint2 wv;                                                                \
        wv.x = (unsigned)v0 | ((unsigned)v1 << 16);                              \
        wv.y = (unsigned)v2 | ((unsigned)v3 << 16);                              \
        unsigned short* const myLds = half ? SL : SH;                            \
        *(uint2*)(myLds + nl * 128 + ((cl >> 1) ^ (nl & 15)) * 8                 \
                  + (cl & 1) * 4) = wv;                                          \
    }                                                                            \
    const int sr = tid >> 3;                                                     \
    const int s0 = (tid & 7) * 2;                                                \
    const size_t gsrc = (size_t)(row0 + sr) * 128 + (tid & 7) * 16;              \
    const int ld0 = sr * 128 + ((s0 + 0) ^ (sr & 15)) * 8;                       \
    const int ld1 = sr * 128 + ((s0 + 1) ^ (sr & 15)) * 8;                       \
    const uint4 rh0 = *(const uint4*)(tabHi + gsrc);                             \
    const uint4 rh1 = *(const uint4*)(tabHi + gsrc + 8);                         \
    const uint4 rl0 = *(const uint4*)(tabLo + gsrc);                             \
    const uint4 rl1 = *(const uint4*)(tabLo + gsrc + 8);                         \
    floatx16 acc;                                                                \
    _Pragma("unroll")                                                            \
    for (int r = 0; r < 16; ++r) acc[r] = 0.f;                                   \
    __syncthreads();                                                             \
    _Pragma("unroll")                                                            \
    for (int kb = 0; kb < 8; ++kb) {                                             \
        const int slot = (2 * kb + kq) ^ (rrow & 15);                            \
        const short8 Ah = *(const short8*)(SH + rrow * 128 + slot * 8);          \
        const short8 Al = *(const short8*)(SL + rrow * 128 + slot * 8);          \
        const size_t wo = ((size_t)(kb * 4 + cb) * 64 + lane) * 8;               \
        const short8 wh = *(const short8*)(Whi + wo);                            \
        const short8 wl = *(const short8*)(Wlo + wo);                            \
        acc = __builtin_amdgcn_mfma_f32_32x32x16_bf16(Ah, wh, acc, 0, 0, 0);     \
        acc = __builtin_amdgcn_mfma_f32_32x32x16_bf16(Al, wh, acc, 0, 0, 0);     \
        acc = __builtin_amdgcn_mfma_f32_32x32x16_bf16(Ah, wl, acc, 0, 0, 0);     \
    }                                                                            \
    __syncthreads();                                                             \
    *(uint4*)(SH + ld0) = rh0;                                                   \
    *(uint4*)(SH + ld1) = rh1;                                                   \
    *(uint4*)(SL + ld0) = rl0;                                                   \
    *(uint4*)(SL + ld1) = rl1;                                                   \
    __syncthreads();                                                             \
    _Pragma("unroll")                                                            \
    for (int kb = 0; kb < 8; ++kb) {                                             \
        const int slot = (2 * kb + kq) ^ (rrow & 15);                            \
        const short8 Ah = *(const short8*)(SH + rrow * 128 + slot * 8);          \
        const short8 Al = *(const short8*)(SL + rrow * 128 + slot * 8);          \
        const size_t wo = ((size_t)((kb + 8) * 4 + cb) * 64 + lane) * 8;         \
        const short8 wh = *(const short8*)(Whi + wo);                            \
        const short8 wl = *(const short8*)(Wlo + wo);                            \
        acc = __builtin_amdgcn_mfma_f32_32x32x16_bf16(Ah, wh, acc, 0, 0, 0);     \
        acc = __builtin_amdgcn_mfma_f32_32x32x16_bf16(Al, wh, acc, 0, 0, 0);     \
        acc = __builtin_amdgcn_mfma_f32_32x32x16_bf16(Ah, wl, acc, 0, 0, 0);     \
    }

__global__ __launch_bounds__(256) void k_fused1(
    const unsigned short* __restrict__ tHi, const unsigned short* __restrict__ tLo,
    const int* __restrict__ rowptr, const unsigned* __restrict__ cw,
    const short* __restrict__ Whi, const short* __restrict__ Wlo,
    const float* __restrict__ bl,
    const float* __restrict__ bng, const float* __restrict__ bnb,
    const float* __restrict__ bnm, const float* __restrict__ bnv,
    unsigned short* __restrict__ outHi, unsigned short* __restrict__ outLo) {
    __shared__ unsigned short SH[32 * 128];
    __shared__ unsigned short SL[32 * 128];
    GEMM_BODY(tHi, tLo)

    // ---- epilogue: bn + relu -> bf16 hi/lo ----
    const int c = cb * 32 + rrow;
    const float s = bng[c] * rsqrtf(bnv[c] + 1e-5f);
    const float t = (bl[c] - bnm[c]) * s + bnb[c];
#pragma unroll
    for (int r = 0; r < 16; ++r) {
        const int row = row0 + (r & 3) + 8 * (r >> 2) + 4 * kq;
        const float v = fmaxf(fmaf(acc[r], s, t), 0.f);
        const unsigned short hb = f2bf(v);
        outHi[(size_t)row * 128 + c] = hb;
        outLo[(size_t)row * 128 + c] = f2bf(v - bf2f(hb));
    }
}

__global__ __launch_bounds__(256) void k_fused2(
    const unsigned short* __restrict__ tHi, const unsigned short* __restrict__ tLo,
    const int* __restrict__ rowptr, const unsigned* __restrict__ cw,
    const short* __restrict__ Whi, const short* __restrict__ Wlo,
    const float* __restrict__ bl,
    const float* __restrict__ bng, const float* __restrict__ bnb,
    const float* __restrict__ bnm, const float* __restrict__ bnv,
    const float* __restrict__ w3l, const float* __restrict__ w3r,
    float* __restrict__ t4) {
    __shared__ unsigned short SH[32 * 128];
    __shared__ unsigned short SL[32 * 128];
    GEMM_BODY(tHi, tLo)

    // ---- epilogue: bn + relu -> v back into swizzled LDS (round-5 verified) ----
    const int c = cb * 32 + rrow;
    const float s = bng[c] * rsqrtf(bnv[c] + 1e-5f);
    const float t = (bl[c] - bnm[c]) * s + bnb[c];
    __syncthreads();          // main-loop reads of SH/SL done
#pragma unroll
    for (int r = 0; r < 16; ++r) {
        const int rl = (r & 3) + 8 * (r >> 2) + 4 * kq;   // local row
        const float v = fmaxf(fmaf(acc[r], s, t), 0.f);
        const unsigned short hb = f2bf(v);
        const int sl = ((c >> 3) ^ (rl & 15)) * 8 + (c & 7);
        SH[rl * 128 + sl] = hb;
        SL[rl * 128 + sl] = f2bf(v - bf2f(hb));
    }
    __syncthreads();

    // ---- wave 0: t4 = v @ [w3l | w3r]  (K = 128, N = 4) ----
    if (tid < 64) {
        const int n = rrow;
        floatx16 a2;
#pragma unroll
        for (int r = 0; r < 16; ++r) a2[r] = 0.f;
#pragma unroll
        for (int kb = 0; kb < 8; ++kb) {
            const int slot = (2 * kb + kq) ^ (rrow & 15);
            const short8 Ah = *(const short8*)(SH + rrow * 128 + slot * 8);
            const short8 Al = *(const short8*)(SL + rrow * 128 + slot * 8);
            short8 Bh, Bl;
            if (n < 4) {
#pragma unroll
                for (int j = 0; j < 8; ++j) {
                    const int k = kb * 16 + kq * 8 + j;
                    const float f = (n < 2) ? w3l[k * 2 + n] : w3r[k * 2 + (n - 2)];
                    const unsigned short hb2 = f2bf(f);
                    Bh[j] = (short)hb2;
                    Bl[j] = (short)f2bf(f - bf2f(hb2));
                }
            } else {
#pragma unroll
                for (int j = 0; j < 8; ++j) { Bh[j] = 0; Bl[j] = 0; }
            }
            a2 = __builtin_amdgcn_mfma_f32_32x32x16_bf16(Ah, Bh, a2, 0, 0, 0);
            a2 = __builtin_amdgcn_mfma_f32_32x32x16_bf16(Al, Bh, a2, 0, 0, 0);
            a2 = __builtin_amdgcn_mfma_f32_32x32x16_bf16(Ah, Bl, a2, 0, 0, 0);
        }
        if (n < 4) {
#pragma unroll
            for (int r = 0; r < 16; ++r) {
                const int row = row0 + (r & 3) + 8 * (r >> 2) + 4 * kq;
                t4[(size_t)row * 4 + n] = a2[r];
            }
        }
    }
}

// ---------------------------------------------------------------- final edge aggregate
__global__ void k_out(const float* __restrict__ t4, const int* __restrict__ rowptr,
                      const unsigned* __restrict__ cw,
                      const float* __restrict__ b3, float* __restrict__ out) {
    const int lane = threadIdx.x & 63;
    const int node = blockIdx.x * (blockDim.x >> 6) + (threadIdx.x >> 6);
    if (node >= N_NODES) return;
    const int s = rowptr[node], e = rowptr[node + 1];
    float a0 = 0.f, a1 = 0.f;
    for (int j = s + lane; j < e; j += 64) {
        const unsigned p = cw[j];
        const int   sr = (int)(p >> 15);
        const float w  = __uint_as_float((p & 0x7FFFu) << 16);
        float2 t = *(const float2*)(t4 + (size_t)sr * 4);
        a0 += w * t.x; a1 += w * t.y;
    }
#pragma unroll
    for (int m = 1; m < 64; m <<= 1) {
        a0 += __shfl_xor(a0, m, 64);
        a1 += __shfl_xor(a1, m, 64);
    }
    if (lane == 0) {
        float inv = 1.f / fmaxf((float)(e - s), 1.f);
        float2 o;
        o.x = a0 * inv + b3[0] + t4[(size_t)node * 4 + 2];
        o.y = a1 * inv + b3[1] + t4[(size_t)node * 4 + 3];
        *(float2*)(out + (size_t)node * 2) = o;
    }
}

// ---------------------------------------------------------------- launch
extern "C" void kernel_launch(void* const* d_in, const int* in_sizes, int n_in,
                              void* d_out, int out_size, void* d_ws, size_t ws_size,
                              hipStream_t stream) {
    const float* x    = (const float*)d_in[0];
    const float* ea   = (const float*)d_in[1];
    const int*   ei   = (const int*)d_in[2];
    const float* ew1w = (const float*)d_in[3];
    const float* ew1b = (const float*)d_in[4];
    const float* ew2w = (const float*)d_in[5];
    const float* ew2b = (const float*)d_in[6];
    const float* w1l  = (const float*)d_in[7];
    const float* b1l  = (const float*)d_in[8];
    const float* w1r  = (const float*)d_in[9];
    const float* w2l  = (const float*)d_in[10];
    const float* b2l  = (const float*)d_in[11];
    const float* w2r  = (const float*)d_in[12];
    const float* w3l  = (const float*)d_in[13];
    const float* b3l  = (const float*)d_in[14];
    const float* w3r  = (const float*)d_in[15];
    const float* bn1g = (const float*)d_in[16];
    const float* bn1b = (const float*)d_in[17];
    const float* bn1m = (const float*)d_in[18];
    const float* bn1v = (const float*)d_in[19];
    const float* bn2g = (const float*)d_in[20];
    const float* bn2b = (const float*)d_in[21];
    const float* bn2m = (const float*)d_in[22];
    const float* bn2v = (const float*)d_in[23];

    const int* src = ei;
    const int* dst = ei + N_EDGES;
    float* out = (float*)d_out;

    size_t off = 0;
    auto carve = [&](size_t bytes) -> void* {
        void* p = (char*)d_ws + off;
        off += (bytes + 255) & ~(size_t)255;
        return p;
    };
    float* ew     = (float*)carve((size_t)N_EDGES * 4);
    unsigned* cw  = (unsigned*)carve((size_t)N_EDGES * 4);
    unsigned char* rank = (unsigned char*)carve((size_t)N_EDGES);
    int*   rowptr = (int*)carve((size_t)(N_NODES + 1) * 4);
    int*   deg    = (int*)carve((size_t)N_NODES * 4);
    int*   bsum   = (int*)carve(128 * 4);
    int*   incl   = (int*)carve((size_t)N_NODES * 4);
    float* t4     = (float*)carve((size_t)N_NODES * 4 * 4);
    short* W1hi   = (short*)carve(32768 * 2);
    short* W1lo   = (short*)carve(32768 * 2);
    short* W2hi   = (short*)carve(32768 * 2);
    short* W2lo   = (short*)carve(32768 * 2);
    unsigned short* xbHi  = (unsigned short*)carve((size_t)N_NODES * 128 * 2);
    unsigned short* xbLo  = (unsigned short*)carve((size_t)N_NODES * 128 * 2);
    unsigned short* hHi   = (unsigned short*)carve((size_t)N_NODES * 128 * 2);
    unsigned short* hLo   = (unsigned short*)carve((size_t)N_NODES * 128 * 2);
    (void)ws_size; (void)n_in; (void)in_sizes; (void)out_size;

    hipMemsetAsync(deg, 0, (size_t)N_NODES * 4, stream);

    const int EB = (N_EDGES + 255) / 256;        // 6250
    const int NB_SCAN = (N_NODES + 1023) / 1024; // 98
    const int NWB = (N_NODES + 3) / 4;           // 25000
    const int GB = N_NODES / 32;                 // 3125 (exact)

    k_front<<<FRONT_GRID, 256, 0, stream>>>(
        x, xbHi, xbLo, dst, deg, rank,
        ea, ew1w, ew1b, ew2w, ew2b, ew,
        w1l, w1r, W1hi, W1lo, w2l, w2r, W2hi, W2lo);
    k_scan1<<<NB_SCAN, 1024, 0, stream>>>(deg, incl, bsum);
    k_scan23<<<(N_NODES + 255) / 256, 256, 0, stream>>>(incl, bsum, rowptr, NB_SCAN);
    k_fill<<<EB, 256, 0, stream>>>(src, dst, ew, rowptr, rank, cw);

    // layer 1 (fused gather + GEMM)
    k_fused1<<<GB, 256, 0, stream>>>(xbHi, xbLo, rowptr, cw, W1hi, W1lo, b1l,
                                     bn1g, bn1b, bn1m, bn1v, hHi, hLo);
    // layer 2 (fused gather + GEMM + MFMA-fused lin3)
    k_fused2<<<GB, 256, 0, stream>>>(hHi, hLo, rowptr, cw, W2hi, W2lo, b2l,
                                     bn2g, bn2b, bn2m, bn2v, w3l, w3r, t4);
    // layer 3 edge aggregate
    k_out<<<NWB, 256, 0, stream>>>(t4, rowptr, cw, b3l, out);
}

// Round 8
// 481.183 us; speedup vs baseline: 1.0585x; 1.0585x over previous
//
#include <hip/hip_runtime.h>
#include <math.h>

#define N_NODES 100000
#define N_EDGES 1600000
#define F_INF   128
#define HIDF    128

#define MLP_BLOCKS  2048
#define CAST_BLOCKS 12500                     // N*128/4/256
#define WP_BASE     (CAST_BLOCKS + MLP_BLOCKS) // 14548
#define FRONT_GRID  (WP_BASE + 256)            // + 2x128 wpack blocks

typedef __attribute__((ext_vector_type(8)))  short short8;
typedef __attribute__((ext_vector_type(16))) float floatx16;

__device__ __forceinline__ unsigned short f2bf(float f) {
    unsigned u = __float_as_uint(f);
    return (unsigned short)((u + 0x7FFFu + ((u >> 16) & 1u)) >> 16);
}
__device__ __forceinline__ float bf2f(unsigned short h) {
    return __uint_as_float((unsigned)h << 16);
}

// ---------------------------------------------------------------- FRONT (merged)
// Verified round-4/6 version (~101 us): cast+degree-atomic / edge-MLP / wpack.
__global__ __launch_bounds__(256) void k_front(
        const float* __restrict__ x,
        unsigned short* __restrict__ xbHi, unsigned short* __restrict__ xbLo,
        const int* __restrict__ dst, int* __restrict__ deg,
        unsigned char* __restrict__ rank,
        const float* __restrict__ ea,
        const float* __restrict__ mw1, const float* __restrict__ mb1,
        const float* __restrict__ mw2, const float* __restrict__ mb2,
        float* __restrict__ ew,
        const float* __restrict__ w1l, const float* __restrict__ w1r,
        short* __restrict__ W1hi, short* __restrict__ W1lo,
        const float* __restrict__ w2l, const float* __restrict__ w2r,
        short* __restrict__ W2hi, short* __restrict__ W2lo) {
    const int bid = blockIdx.x;

    if (bid >= WP_BASE) {
        const int wb  = bid - WP_BASE;                   // 0..255
        const int idx = (wb & 127) * 256 + threadIdx.x;  // 0..32767
        const float* Wl = (wb < 128) ? w1l : w2l;
        const float* Wr = (wb < 128) ? w1r : w2r;
        short* Whi = (wb < 128) ? W1hi : W2hi;
        short* Wlo = (wb < 128) ? W1lo : W2lo;
        const int j  = idx & 7;
        const int L  = (idx >> 3) & 63;
        const int cb = (idx >> 9) & 3;
        const int kb = (idx >> 11);
        const int k  = kb * 16 + (L >> 5) * 8 + j;
        const int n  = cb * 32 + (L & 31);
        const float a = (k < 128) ? Wl[k * 128 + n] : Wr[(k - 128) * 128 + n];
        const unsigned short hb = f2bf(a);
        Whi[idx] = (short)hb;
        Wlo[idx] = (short)f2bf(a - bf2f(hb));
        return;
    }

    const bool is_mlp = ((bid % 7) == 3) && (bid < 7 * MLP_BLOCKS);
    if (!is_mlp) {
        const int c   = (bid < 4) ? 0 : min(MLP_BLOCKS, (bid - 4) / 7 + 1);
        const int gid = (bid - c) * 256 + (int)threadIdx.x;   // 0 .. 3.2M-1
        const int i   = gid * 4;                              // N*128 exactly
        const float4 v = *(const float4*)(x + i);
        ushort4 h, l;
        h.x = f2bf(v.x); l.x = f2bf(v.x - bf2f(h.x));
        h.y = f2bf(v.y); l.y = f2bf(v.y - bf2f(h.y));
        h.z = f2bf(v.z); l.z = f2bf(v.z - bf2f(h.z));
        h.w = f2bf(v.w); l.w = f2bf(v.w - bf2f(h.w));
        *(ushort4*)(xbHi + i) = h;
        *(ushort4*)(xbLo + i) = l;
        if ((gid & 1) == 0) {
            const int e = gid >> 1;                           // covers all 1.6M edges
            rank[e] = (unsigned char)atomicAdd(&deg[dst[e]], 1);
        }
        return;
    }

    // ---- edge MLP (wave = 32 edges; grid-stride over 8192 waves) ----
    const int lane = threadIdx.x & 63;
    const int cl   = lane & 31;
    const int half = lane >> 5;
    const int wid  = (bid / 7) * 4 + ((int)threadIdx.x >> 6);
    const int nw   = MLP_BLOCKS * 4;

    short8 bw[4];
    float  w2c[4];
#pragma unroll
    for (int cb = 0; cb < 4; ++cb) {
        const int n = cb * 32 + cl;
        short8 b;
        if (half == 0) {
#pragma unroll
            for (int j = 0; j < 8; ++j) b[j] = (short)f2bf(mw1[j * 128 + n]);
        } else {
            b[0] = (short)f2bf(mb1[n]);
#pragma unroll
            for (int j = 1; j < 8; ++j) b[j] = 0;
        }
        bw[cb] = b;
        w2c[cb] = mw2[n];
    }
    short8 Abias;
    Abias[0] = (short)0x3F80;
#pragma unroll
    for (int j = 1; j < 8; ++j) Abias[j] = 0;

    floatx16 czero;
#pragma unroll
    for (int r = 0; r < 16; ++r) czero[r] = 0.f;

    const float bias2 = mb2[0];

    for (int e0 = wid * 32; e0 < N_EDGES; e0 += nw * 32) {
        short8 Ah;
        if (half == 0) {
            const float4 a0 = *(const float4*)(ea + (size_t)(e0 + cl) * 8);
            const float4 a1 = *(const float4*)(ea + (size_t)(e0 + cl) * 8 + 4);
            Ah[0] = (short)f2bf(a0.x); Ah[1] = (short)f2bf(a0.y);
            Ah[2] = (short)f2bf(a0.z); Ah[3] = (short)f2bf(a0.w);
            Ah[4] = (short)f2bf(a1.x); Ah[5] = (short)f2bf(a1.y);
            Ah[6] = (short)f2bf(a1.z); Ah[7] = (short)f2bf(a1.w);
        } else {
            Ah = Abias;
        }

        float z[16];
#pragma unroll
        for (int r = 0; r < 16; ++r) z[r] = 0.f;

#pragma unroll
        for (int cb = 0; cb < 4; ++cb) {
            floatx16 acc = __builtin_amdgcn_mfma_f32_32x32x16_bf16(Ah, bw[cb], czero, 0, 0, 0);
#pragma unroll
            for (int r = 0; r < 16; ++r)
                z[r] = fmaf(fmaxf(acc[r], 0.f), w2c[cb], z[r]);
        }

#pragma unroll
        for (int m = 1; m <= 16; m <<= 1) {
#pragma unroll
            for (int r = 0; r < 16; ++r) z[r] += __shfl_xor(z[r], m, 64);
        }

        float zz = z[0];
#pragma unroll
        for (int r = 1; r < 16; ++r) zz = (cl == r) ? z[r] : zz;
        if (cl < 16) {
            const int row = (cl & 3) + 8 * (cl >> 2) + 4 * half;
            ew[e0 + row] = 1.f / (1.f + __expf(-(zz + bias2)));
        }
    }
}

// ---------------------------------------------------------------- CSR build
__global__ void k_scan1(const int* __restrict__ deg, int* __restrict__ incl,
                        int* __restrict__ bsum) {
    __shared__ int sm[1024];
    const int tid = threadIdx.x;
    const int gi  = blockIdx.x * 1024 + tid;
    int v = (gi < N_NODES) ? deg[gi] : 0;
    sm[tid] = v;
    __syncthreads();
    for (int off = 1; off < 1024; off <<= 1) {
        int t = (tid >= off) ? sm[tid - off] : 0;
        __syncthreads();
        sm[tid] += t;
        __syncthreads();
    }
    if (gi < N_NODES) incl[gi] = sm[tid];
    if (tid == 1023) bsum[blockIdx.x] = sm[1023];
}

__global__ void k_scan23(const int* __restrict__ incl, const int* __restrict__ bsum,
                         int* __restrict__ rowptr, int nb) {
    __shared__ int sm[128];
    const int tid = threadIdx.x;   // 256
    int v = 0;
    if (tid < 128) {
        v = (tid < nb) ? bsum[tid] : 0;
        sm[tid] = v;
    }
    __syncthreads();
    for (int off = 1; off < 128; off <<= 1) {
        int t = 0;
        if (tid < 128 && tid >= off) t = sm[tid - off];
        __syncthreads();
        if (tid < 128) sm[tid] += t;
        __syncthreads();
    }
    if (tid < 128) sm[tid] -= v;   // exclusive block offset
    __syncthreads();
    const int i = blockIdx.x * 256 + tid;
    if (i < N_NODES) rowptr[i + 1] = sm[i >> 10] + incl[i];
    if (i == 0) rowptr[0] = 0;
}

__global__ void k_fill(const int* __restrict__ src, const int* __restrict__ dst,
                       const float* __restrict__ ew, const int* __restrict__ rowptr,
                       const unsigned char* __restrict__ rank,
                       unsigned* __restrict__ cw) {
    int e = blockIdx.x * 256 + threadIdx.x;
    if (e < N_EDGES) {
        int d   = dst[e];
        int pos = rowptr[d] + (int)rank[e];
        unsigned wb = (unsigned)f2bf(ew[e]) & 0x7FFFu;
        cw[pos] = ((unsigned)src[e] << 15) | wb;
    }
}

// ---------------------------------------------------------------- aggregation (quad bf16 gather)
// SPLIT structure restored (fusion lost twice: gather wants max TLP, hates
// sharing a barrier with MFMA). New quad layout: 16 lanes x 16B (uint4) per
// edge row = half the VMEM instructions of the old 32x8B, 4 edges per
// wave-instr, 16 in flight. All 64 lanes share one node, so tail clamps are
// same-address L1 hits. Epilogue writes bf16 hi/lo as before.
__global__ __launch_bounds__(256) void k_agg16(
        const unsigned short* __restrict__ xb, const int* __restrict__ rowptr,
        const unsigned* __restrict__ cw,
        unsigned short* __restrict__ aggHi, unsigned short* __restrict__ aggLo) {
    const int lane = threadIdx.x & 63;
    const int grp  = lane >> 4;          // which edge of the quad
    const int cl   = lane & 15;          // cols cl*8 .. cl*8+7
    const int node = blockIdx.x * (blockDim.x >> 6) + (threadIdx.x >> 6);
    if (node >= N_NODES) return;
    const int s = rowptr[node], e = rowptr[node + 1];
    float a[8];
#pragma unroll
    for (int k = 0; k < 8; ++k) a[k] = 0.f;

    for (int j0 = s; j0 < e; j0 += 16) {
        int ss[4]; float ww[4];
#pragma unroll
        for (int u = 0; u < 4; ++u) {
            const int j  = j0 + 4 * u + grp;
            const int jc = min(j, e - 1);
            const unsigned p = cw[jc];
            ss[u] = (int)(p >> 15);
            ww[u] = (j < e) ? __uint_as_float((p & 0x7FFFu) << 16) : 0.f;
        }
        uint4 g[4];
#pragma unroll
        for (int u = 0; u < 4; ++u)
            g[u] = *(const uint4*)(xb + (size_t)ss[u] * 128 + cl * 8);
#pragma unroll
        for (int u = 0; u < 4; ++u) {
            const unsigned gw[4] = {g[u].x, g[u].y, g[u].z, g[u].w};
#pragma unroll
            for (int k = 0; k < 4; ++k) {
                const float f0 = __uint_as_float(gw[k] << 16);
                const float f1 = __uint_as_float(gw[k] & 0xFFFF0000u);
                a[2 * k]     = fmaf(ww[u], f0, a[2 * k]);
                a[2 * k + 1] = fmaf(ww[u], f1, a[2 * k + 1]);
            }
        }
    }
    // reduce across the 4 quad groups
#pragma unroll
    for (int k = 0; k < 8; ++k) {
        a[k] += __shfl_xor(a[k], 16, 64);
        a[k] += __shfl_xor(a[k], 32, 64);
    }
    if (lane < 16) {
        const float inv = 1.f / fmaxf((float)(e - s), 1.f);
        uint4 H, L;
        unsigned hw[4], lw[4];
#pragma unroll
        for (int k = 0; k < 4; ++k) {
            const float v0 = a[2 * k] * inv;
            const float v1 = a[2 * k + 1] * inv;
            const unsigned short h0 = f2bf(v0), h1 = f2bf(v1);
            const unsigned short l0 = f2bf(v0 - bf2f(h0)), l1 = f2bf(v1 - bf2f(h1));
            hw[k] = (unsigned)h0 | ((unsigned)h1 << 16);
            lw[k] = (unsigned)l0 | ((unsigned)l1 << 16);
        }
        H.x = hw[0]; H.y = hw[1]; H.z = hw[2]; H.w = hw[3];
        L.x = lw[0]; L.y = lw[1]; L.z = lw[2]; L.w = lw[3];
        *(uint4*)(aggHi + (size_t)node * 128 + cl * 8) = H;
        *(uint4*)(aggLo + (size_t)node * 128 + cl * 8) = L;
    }
}

// ---------------------------------------------------------------- MFMA GEMM layer 1 (LDS-staged A)
__global__ __launch_bounds__(256) void k_gemm(
    const unsigned short* __restrict__ AaggHi, const unsigned short* __restrict__ AaggLo,
    const unsigned short* __restrict__ AxHi, const unsigned short* __restrict__ AxLo,
    const short* __restrict__ Whi, const short* __restrict__ Wlo,
    const float* __restrict__ bl,
    const float* __restrict__ bng, const float* __restrict__ bnb,
    const float* __restrict__ bnm, const float* __restrict__ bnv,
    unsigned short* __restrict__ outHi, unsigned short* __restrict__ outLo) {
    __shared__ unsigned short SH[32 * 128];
    __shared__ unsigned short SL[32 * 128];
    const int tid  = threadIdx.x;
    const int lane = tid & 63;
    const int cb   = tid >> 6;
    const int rrow = lane & 31;
    const int kq   = lane >> 5;
    const int row0 = blockIdx.x * 32;

    const int sr = tid >> 3;
    const int sc = (tid & 7) * 16;
    const int s0 = sc >> 3;
    const size_t gsrc = (size_t)(row0 + sr) * 128 + sc;
    const int ld0 = sr * 128 + ((s0 + 0) ^ (sr & 15)) * 8;
    const int ld1 = sr * 128 + ((s0 + 1) ^ (sr & 15)) * 8;

    const uint4 ah0 = *(const uint4*)(AaggHi + gsrc);
    const uint4 ah1 = *(const uint4*)(AaggHi + gsrc + 8);
    const uint4 al0 = *(const uint4*)(AaggLo + gsrc);
    const uint4 al1 = *(const uint4*)(AaggLo + gsrc + 8);
    const uint4 rh0 = *(const uint4*)(AxHi + gsrc);
    const uint4 rh1 = *(const uint4*)(AxHi + gsrc + 8);
    const uint4 rl0 = *(const uint4*)(AxLo + gsrc);
    const uint4 rl1 = *(const uint4*)(AxLo + gsrc + 8);

    *(uint4*)(SH + ld0) = ah0;
    *(uint4*)(SH + ld1) = ah1;
    *(uint4*)(SL + ld0) = al0;
    *(uint4*)(SL + ld1) = al1;

    floatx16 acc;
#pragma unroll
    for (int r = 0; r < 16; ++r) acc[r] = 0.f;

    __syncthreads();

#pragma unroll
    for (int kb = 0; kb < 8; ++kb) {
        const int slot = (2 * kb + kq) ^ (rrow & 15);
        const short8 Ah = *(const short8*)(SH + rrow * 128 + slot * 8);
        const short8 Al = *(const short8*)(SL + rrow * 128 + slot * 8);
        const size_t wo = ((size_t)(kb * 4 + cb) * 64 + lane) * 8;
        const short8 wh = *(const short8*)(Whi + wo);
        const short8 wl = *(const short8*)(Wlo + wo);
        acc = __builtin_amdgcn_mfma_f32_32x32x16_bf16(Ah, wh, acc, 0, 0, 0);
        acc = __builtin_amdgcn_mfma_f32_32x32x16_bf16(Al, wh, acc, 0, 0, 0);
        acc = __builtin_amdgcn_mfma_f32_32x32x16_bf16(Ah, wl, acc, 0, 0, 0);
    }

    __syncthreads();
    *(uint4*)(SH + ld0) = rh0;
    *(uint4*)(SH + ld1) = rh1;
    *(uint4*)(SL + ld0) = rl0;
    *(uint4*)(SL + ld1) = rl1;
    __syncthreads();

#pragma unroll
    for (int kb = 0; kb < 8; ++kb) {
        const int slot = (2 * kb + kq) ^ (rrow & 15);
        const short8 Ah = *(const short8*)(SH + rrow * 128 + slot * 8);
        const short8 Al = *(const short8*)(SL + rrow * 128 + slot * 8);
        const size_t wo = ((size_t)((kb + 8) * 4 + cb) * 64 + lane) * 8;
        const short8 wh = *(const short8*)(Whi + wo);
        const short8 wl = *(const short8*)(Wlo + wo);
        acc = __builtin_amdgcn_mfma_f32_32x32x16_bf16(Ah, wh, acc, 0, 0, 0);
        acc = __builtin_amdgcn_mfma_f32_32x32x16_bf16(Al, wh, acc, 0, 0, 0);
        acc = __builtin_amdgcn_mfma_f32_32x32x16_bf16(Ah, wl, acc, 0, 0, 0);
    }

    const int c = cb * 32 + rrow;
    const float s = bng[c] * rsqrtf(bnv[c] + 1e-5f);
    const float t = (bl[c] - bnm[c]) * s + bnb[c];
#pragma unroll
    for (int r = 0; r < 16; ++r) {
        const int row = row0 + (r & 3) + 8 * (r >> 2) + 4 * kq;
        const float v = fmaxf(fmaf(acc[r], s, t), 0.f);
        const unsigned short hb = f2bf(v);
        outHi[(size_t)row * 128 + c] = hb;
        outLo[(size_t)row * 128 + c] = f2bf(v - bf2f(hb));
    }
}

// ---------------------------------------------------------------- MFMA GEMM layer 2 (+ MFMA-fused lin3)
// Round-5/6 verified: epilogue writes bn-relu'd v back into swizzled LDS;
// wave 0 computes t4 = v @ [w3l|w3r] as a 24-MFMA chain.
__global__ __launch_bounds__(256) void k_gemm2(
    const unsigned short* __restrict__ AaggHi, const unsigned short* __restrict__ AaggLo,
    const unsigned short* __restrict__ AxHi, const unsigned short* __restrict__ AxLo,
    const short* __restrict__ Whi, const short* __restrict__ Wlo,
    const float* __restrict__ bl,
    const float* __restrict__ bng, const float* __restrict__ bnb,
    const float* __restrict__ bnm, const float* __restrict__ bnv,
    const float* __restrict__ w3l, const float* __restrict__ w3r,
    float* __restrict__ t4) {
    __shared__ unsigned short SH[32 * 128];
    __shared__ unsigned short SL[32 * 128];
    const int tid  = threadIdx.x;
    const int lane = tid & 63;
    const int cb   = tid >> 6;
    const int rrow = lane & 31;
    const int kq   = lane >> 5;
    const int row0 = blockIdx.x * 32;

    const int sr = tid >> 3;
    const int sc = (tid & 7) * 16;
    const int s0 = sc >> 3;
    const size_t gsrc = (size_t)(row0 + sr) * 128 + sc;
    const int ld0 = sr * 128 + ((s0 + 0) ^ (sr & 15)) * 8;
    const int ld1 = sr * 128 + ((s0 + 1) ^ (sr & 15)) * 8;

    const uint4 ah0 = *(const uint4*)(AaggHi + gsrc);
    const uint4 ah1 = *(const uint4*)(AaggHi + gsrc + 8);
    const uint4 al0 = *(const uint4*)(AaggLo + gsrc);
    const uint4 al1 = *(const uint4*)(AaggLo + gsrc + 8);
    const uint4 rh0 = *(const uint4*)(AxHi + gsrc);
    const uint4 rh1 = *(const uint4*)(AxHi + gsrc + 8);
    const uint4 rl0 = *(const uint4*)(AxLo + gsrc);
    const uint4 rl1 = *(const uint4*)(AxLo + gsrc + 8);

    *(uint4*)(SH + ld0) = ah0;
    *(uint4*)(SH + ld1) = ah1;
    *(uint4*)(SL + ld0) = al0;
    *(uint4*)(SL + ld1) = al1;

    floatx16 acc;
#pragma unroll
    for (int r = 0; r < 16; ++r) acc[r] = 0.f;

    __syncthreads();

#pragma unroll
    for (int kb = 0; kb < 8; ++kb) {
        const int slot = (2 * kb + kq) ^ (rrow & 15);
        const short8 Ah = *(const short8*)(SH + rrow * 128 + slot * 8);
        const short8 Al = *(const short8*)(SL + rrow * 128 + slot * 8);
        const size_t wo = ((size_t)(kb * 4 + cb) * 64 + lane) * 8;
        const short8 wh = *(const short8*)(Whi + wo);
        const short8 wl = *(const short8*)(Wlo + wo);
        acc = __builtin_amdgcn_mfma_f32_32x32x16_bf16(Ah, wh, acc, 0, 0, 0);
        acc = __builtin_amdgcn_mfma_f32_32x32x16_bf16(Al, wh, acc, 0, 0, 0);
        acc = __builtin_amdgcn_mfma_f32_32x32x16_bf16(Ah, wl, acc, 0, 0, 0);
    }

    __syncthreads();
    *(uint4*)(SH + ld0) = rh0;
    *(uint4*)(SH + ld1) = rh1;
    *(uint4*)(SL + ld0) = rl0;
    *(uint4*)(SL + ld1) = rl1;
    __syncthreads();

#pragma unroll
    for (int kb = 0; kb < 8; ++kb) {
        const int slot = (2 * kb + kq) ^ (rrow & 15);
        const short8 Ah = *(const short8*)(SH + rrow * 128 + slot * 8);
        const short8 Al = *(const short8*)(SL + rrow * 128 + slot * 8);
        const size_t wo = ((size_t)((kb + 8) * 4 + cb) * 64 + lane) * 8;
        const short8 wh = *(const short8*)(Whi + wo);
        const short8 wl = *(const short8*)(Wlo + wo);
        acc = __builtin_amdgcn_mfma_f32_32x32x16_bf16(Ah, wh, acc, 0, 0, 0);
        acc = __builtin_amdgcn_mfma_f32_32x32x16_bf16(Al, wh, acc, 0, 0, 0);
        acc = __builtin_amdgcn_mfma_f32_32x32x16_bf16(Ah, wl, acc, 0, 0, 0);
    }

    // ---- epilogue: bn + relu -> v into the SAME swizzled LDS layout ----
    const int c = cb * 32 + rrow;
    const float s = bng[c] * rsqrtf(bnv[c] + 1e-5f);
    const float t = (bl[c] - bnm[c]) * s + bnb[c];
    __syncthreads();          // main-loop reads of SH/SL done
#pragma unroll
    for (int r = 0; r < 16; ++r) {
        const int rl = (r & 3) + 8 * (r >> 2) + 4 * kq;   // local row
        const float v = fmaxf(fmaf(acc[r], s, t), 0.f);
        const unsigned short hb = f2bf(v);
        const int sl = ((c >> 3) ^ (rl & 15)) * 8 + (c & 7);
        SH[rl * 128 + sl] = hb;
        SL[rl * 128 + sl] = f2bf(v - bf2f(hb));
    }
    __syncthreads();

    // ---- wave 0: t4 = v @ [w3l | w3r]  (K = 128, N = 4) ----
    if (tid < 64) {
        const int n = rrow;
        floatx16 a2;
#pragma unroll
        for (int r = 0; r < 16; ++r) a2[r] = 0.f;
#pragma unroll
        for (int kb = 0; kb < 8; ++kb) {
            const int slot = (2 * kb + kq) ^ (rrow & 15);
            const short8 Ah = *(const short8*)(SH + rrow * 128 + slot * 8);
            const short8 Al = *(const short8*)(SL + rrow * 128 + slot * 8);
            short8 Bh, Bl;
            if (n < 4) {
#pragma unroll
                for (int j = 0; j < 8; ++j) {
                    const int k = kb * 16 + kq * 8 + j;
                    const float f = (n < 2) ? w3l[k * 2 + n] : w3r[k * 2 + (n - 2)];
                    const unsigned short hb2 = f2bf(f);
                    Bh[j] = (short)hb2;
                    Bl[j] = (short)f2bf(f - bf2f(hb2));
                }
            } else {
#pragma unroll
                for (int j = 0; j < 8; ++j) { Bh[j] = 0; Bl[j] = 0; }
            }
            a2 = __builtin_amdgcn_mfma_f32_32x32x16_bf16(Ah, Bh, a2, 0, 0, 0);
            a2 = __builtin_amdgcn_mfma_f32_32x32x16_bf16(Al, Bh, a2, 0, 0, 0);
            a2 = __builtin_amdgcn_mfma_f32_32x32x16_bf16(Ah, Bl, a2, 0, 0, 0);
        }
        if (n < 4) {
#pragma unroll
            for (int r = 0; r < 16; ++r) {
                const int row = row0 + (r & 3) + 8 * (r >> 2) + 4 * kq;
                t4[(size_t)row * 4 + n] = a2[r];
            }
        }
    }
}

// ---------------------------------------------------------------- final edge aggregate
// 16 lanes per node (avg degree 16): 4 nodes/wave, 4x fewer waves, no 75%
// lane idling. Node geometry is wave-subgroup-local; shfl_xor m<16 stays
// within each 16-lane group.
__global__ void k_out(const float* __restrict__ t4, const int* __restrict__ rowptr,
                      const unsigned* __restrict__ cw,
                      const float* __restrict__ b3, float* __restrict__ out) {
    const int lane = threadIdx.x & 63;
    const int nsub = lane >> 4;
    const int l16  = lane & 15;
    const int node = (blockIdx.x * (blockDim.x >> 6) + ((int)threadIdx.x >> 6)) * 4 + nsub;
    if (node >= N_NODES) return;
    const int s = rowptr[node], e = rowptr[node + 1];
    float a0 = 0.f, a1 = 0.f;
    for (int j = s + l16; j < e; j += 16) {
        const unsigned p = cw[j];
        const int   sr = (int)(p >> 15);
        const float w  = __uint_as_float((p & 0x7FFFu) << 16);
        float2 t = *(const float2*)(t4 + (size_t)sr * 4);
        a0 += w * t.x; a1 += w * t.y;
    }
#pragma unroll
    for (int m = 1; m < 16; m <<= 1) {
        a0 += __shfl_xor(a0, m, 64);
        a1 += __shfl_xor(a1, m, 64);
    }
    if (l16 == 0) {
        float inv = 1.f / fmaxf((float)(e - s), 1.f);
        float2 o;
        o.x = a0 * inv + b3[0] + t4[(size_t)node * 4 + 2];
        o.y = a1 * inv + b3[1] + t4[(size_t)node * 4 + 3];
        *(float2*)(out + (size_t)node * 2) = o;
    }
}

// ---------------------------------------------------------------- launch
extern "C" void kernel_launch(void* const* d_in, const int* in_sizes, int n_in,
                              void* d_out, int out_size, void* d_ws, size_t ws_size,
                              hipStream_t stream) {
    const float* x    = (const float*)d_in[0];
    const float* ea   = (const float*)d_in[1];
    const int*   ei   = (const int*)d_in[2];
    const float* ew1w = (const float*)d_in[3];
    const float* ew1b = (const float*)d_in[4];
    const float* ew2w = (const float*)d_in[5];
    const float* ew2b = (const float*)d_in[6];
    const float* w1l  = (const float*)d_in[7];
    const float* b1l  = (const float*)d_in[8];
    const float* w1r  = (const float*)d_in[9];
    const float* w2l  = (const float*)d_in[10];
    const float* b2l  = (const float*)d_in[11];
    const float* w2r  = (const float*)d_in[12];
    const float* w3l  = (const float*)d_in[13];
    const float* b3l  = (const float*)d_in[14];
    const float* w3r  = (const float*)d_in[15];
    const float* bn1g = (const float*)d_in[16];
    const float* bn1b = (const float*)d_in[17];
    const float* bn1m = (const float*)d_in[18];
    const float* bn1v = (const float*)d_in[19];
    const float* bn2g = (const float*)d_in[20];
    const float* bn2b = (const float*)d_in[21];
    const float* bn2m = (const float*)d_in[22];
    const float* bn2v = (const float*)d_in[23];

    const int* src = ei;
    const int* dst = ei + N_EDGES;
    float* out = (float*)d_out;

    size_t off = 0;
    auto carve = [&](size_t bytes) -> void* {
        void* p = (char*)d_ws + off;
        off += (bytes + 255) & ~(size_t)255;
        return p;
    };
    float* ew     = (float*)carve((size_t)N_EDGES * 4);
    unsigned* cw  = (unsigned*)carve((size_t)N_EDGES * 4);
    unsigned char* rank = (unsigned char*)carve((size_t)N_EDGES);
    int*   rowptr = (int*)carve((size_t)(N_NODES + 1) * 4);
    int*   deg    = (int*)carve((size_t)N_NODES * 4);
    int*   bsum   = (int*)carve(128 * 4);
    int*   incl   = (int*)carve((size_t)N_NODES * 4);
    float* t4     = (float*)carve((size_t)N_NODES * 4 * 4);
    short* W1hi   = (short*)carve(32768 * 2);
    short* W1lo   = (short*)carve(32768 * 2);
    short* W2hi   = (short*)carve(32768 * 2);
    short* W2lo   = (short*)carve(32768 * 2);
    unsigned short* xbHi  = (unsigned short*)carve((size_t)N_NODES * 128 * 2);
    unsigned short* xbLo  = (unsigned short*)carve((size_t)N_NODES * 128 * 2);
    unsigned short* aggHi = (unsigned short*)carve((size_t)N_NODES * 128 * 2);
    unsigned short* aggLo = (unsigned short*)carve((size_t)N_NODES * 128 * 2);
    unsigned short* hHi   = (unsigned short*)carve((size_t)N_NODES * 128 * 2);
    unsigned short* hLo   = (unsigned short*)carve((size_t)N_NODES * 128 * 2);
    (void)ws_size; (void)n_in; (void)in_sizes; (void)out_size;

    hipMemsetAsync(deg, 0, (size_t)N_NODES * 4, stream);

    const int EB = (N_EDGES + 255) / 256;        // 6250
    const int NB_SCAN = (N_NODES + 1023) / 1024; // 98
    const int NWB = (N_NODES + 3) / 4;           // 25000
    const int OWB = (N_NODES + 15) / 16;         // 6250
    const int GB = N_NODES / 32;                 // 3125 (exact)

    k_front<<<FRONT_GRID, 256, 0, stream>>>(
        x, xbHi, xbLo, dst, deg, rank,
        ea, ew1w, ew1b, ew2w, ew2b, ew,
        w1l, w1r, W1hi, W1lo, w2l, w2r, W2hi, W2lo);
    k_scan1<<<NB_SCAN, 1024, 0, stream>>>(deg, incl, bsum);
    k_scan23<<<(N_NODES + 255) / 256, 256, 0, stream>>>(incl, bsum, rowptr, NB_SCAN);
    k_fill<<<EB, 256, 0, stream>>>(src, dst, ew, rowptr, rank, cw);

    // layer 1
    k_agg16<<<NWB, 256, 0, stream>>>(xbHi, rowptr, cw, aggHi, aggLo);
    k_gemm<<<GB, 256, 0, stream>>>(aggHi, aggLo, xbHi, xbLo, W1hi, W1lo, b1l,
                                   bn1g, bn1b, bn1m, bn1v, hHi, hLo);
    // layer 2 (+ MFMA-fused lin3 -> t4)
    k_agg16<<<NWB, 256, 0, stream>>>(hHi, rowptr, cw, aggHi, aggLo);
    k_gemm2<<<GB, 256, 0, stream>>>(aggHi, aggLo, hHi, hLo, W2hi, W2lo, b2l,
                                    bn2g, bn2b, bn2m, bn2v, w3l, w3r, t4);
    // layer 3 edge aggregate
    k_out<<<OWB, 256, 0, stream>>>(t4, rowptr, cw, b3l, out);
}